// Round 1
// baseline (18774.428 us; speedup 1.0000x reference)
//
#include <hip/hip_runtime.h>
#include <hip/hip_bf16.h>

// RNN: h_t = tanh(x_t @ Wx + h_{t-1} @ Wh + b), B=32, S=1024, D=H=1024, fp32.
// Phase 1: Xp = x@Wx + b written in-place into d_out (each slot later overwritten by h_t).
// Phase 2: 1023 sequential step launches (correctness baseline; persistent kernel later).

#define BB 32
#define SS 1024
#define DD 1024
#define HH 1024

// ---------------- Phase 1: C[m][n] = A[m][:] @ W[:][n] + bias[n] ----------------
// M=32768, N=1024, K=1024. BM=BN=128, BK=8, 256 threads, 8x8 per thread.
// Micro-tile split as rows {ty*4..+3, 64+ty*4..+3} x cols {tx*4..+3, 64+tx*4..+3}
// so all LDS reads are <=2-way bank aliased (free per m136).
__global__ __launch_bounds__(256) void xw_gemm(const float* __restrict__ A,
                                               const float* __restrict__ W,
                                               const float* __restrict__ bias,
                                               float* __restrict__ C) {
    __shared__ float As[8][132];
    __shared__ float Bs[8][132];
    const int tid = threadIdx.x;
    const int n0 = blockIdx.x * 128;
    const int m0 = blockIdx.y * 128;
    const int tx = tid & 15;
    const int ty = tid >> 4;

    // loader indices
    const int ar = tid >> 1;          // 0..127 (A row)
    const int ak = (tid & 1) * 4;     // 0 or 4 (A k-offset)
    const int bk = tid >> 5;          // 0..7   (B k-row)
    const int bn = (tid & 31) * 4;    // 0..124 (B col)

    float acc[8][8];
#pragma unroll
    for (int i = 0; i < 8; ++i)
#pragma unroll
        for (int j = 0; j < 8; ++j) acc[i][j] = 0.f;

    for (int k0 = 0; k0 < DD; k0 += 8) {
        float4 av = *(const float4*)(A + (size_t)(m0 + ar) * DD + k0 + ak);
        float4 bv = *(const float4*)(W + (size_t)(k0 + bk) * HH + n0 + bn);
        __syncthreads();   // previous iteration's LDS reads done
        As[ak + 0][ar] = av.x;
        As[ak + 1][ar] = av.y;
        As[ak + 2][ar] = av.z;
        As[ak + 3][ar] = av.w;
        *(float4*)&Bs[bk][bn] = bv;
        __syncthreads();
#pragma unroll
        for (int k = 0; k < 8; ++k) {
            float4 a0 = *(const float4*)&As[k][ty * 4];
            float4 a1 = *(const float4*)&As[k][64 + ty * 4];
            float4 b0 = *(const float4*)&Bs[k][tx * 4];
            float4 b1 = *(const float4*)&Bs[k][64 + tx * 4];
            float ar_[8] = {a0.x, a0.y, a0.z, a0.w, a1.x, a1.y, a1.z, a1.w};
            float br_[8] = {b0.x, b0.y, b0.z, b0.w, b1.x, b1.y, b1.z, b1.w};
#pragma unroll
            for (int i = 0; i < 8; ++i)
#pragma unroll
                for (int j = 0; j < 8; ++j)
                    acc[i][j] = fmaf(ar_[i], br_[j], acc[i][j]);
        }
    }

    float4 bv0 = *(const float4*)(bias + n0 + tx * 4);
    float4 bv1 = *(const float4*)(bias + n0 + 64 + tx * 4);
#pragma unroll
    for (int i = 0; i < 8; ++i) {
        int m = m0 + ((i < 4) ? (ty * 4 + i) : (64 + ty * 4 + (i - 4)));
        float4 r0 = {acc[i][0] + bv0.x, acc[i][1] + bv0.y,
                     acc[i][2] + bv0.z, acc[i][3] + bv0.w};
        float4 r1 = {acc[i][4] + bv1.x, acc[i][5] + bv1.y,
                     acc[i][6] + bv1.z, acc[i][7] + bv1.w};
        *(float4*)(C + (size_t)m * HH + n0 + tx * 4) = r0;
        *(float4*)(C + (size_t)m * HH + n0 + 64 + tx * 4) = r1;
    }
}

// ---------------- c[n] = h0 @ Wh (handles nonzero h0 generally) ----------------
__global__ __launch_bounds__(256) void h0wh(const float* __restrict__ Wh,
                                            const float* __restrict__ h0,
                                            float* __restrict__ c) {
    const int g = blockIdx.x;   // 64 groups of 16 k-rows
    const int n = threadIdx.x * 4;
    float4 a = {0.f, 0.f, 0.f, 0.f};
    for (int kk = 0; kk < 16; ++kk) {
        int k = g * 16 + kk;
        float hv = h0[k];
        float4 w = *(const float4*)(Wh + (size_t)k * HH + n);
        a.x += hv * w.x; a.y += hv * w.y; a.z += hv * w.z; a.w += hv * w.w;
    }
    atomicAdd(&c[n + 0], a.x);
    atomicAdd(&c[n + 1], a.y);
    atomicAdd(&c[n + 2], a.z);
    atomicAdd(&c[n + 3], a.w);
}

// ---------------- WhT[n][k] = Wh[k][n] (ws permitting) ----------------
__global__ __launch_bounds__(256) void transpose_wh(const float* __restrict__ in,
                                                    float* __restrict__ outT) {
    __shared__ float tile[32][33];
    const int tx = threadIdx.x & 31;
    const int ty = threadIdx.x >> 5;   // 0..7
    const int x0 = blockIdx.x * 32;
    const int y0 = blockIdx.y * 32;
    for (int r = ty; r < 32; r += 8)
        tile[r][tx] = in[(size_t)(y0 + r) * HH + x0 + tx];
    __syncthreads();
    for (int r = ty; r < 32; r += 8)
        outT[(size_t)(x0 + r) * HH + y0 + tx] = tile[tx][r];
}

// ---------------- t = 0: out[b][0][n] = tanh(Xp + c[n]) ----------------
__global__ __launch_bounds__(256) void t0_kernel(float* __restrict__ out,
                                                 const float* __restrict__ c) {
    const int idx = blockIdx.x * 256 + threadIdx.x;  // 32*1024
    const int b = idx >> 10;
    const int n = idx & 1023;
    const size_t p = (size_t)b * SS * HH + n;
    out[p] = tanhf(out[p] + c[n]);
}

// ---------------- step t: out[b][t][n] = tanh(Xp + h_{t-1}@Wh) ----------------
// grid (64 col-groups, 4 batch-groups), 256 threads. Tile: 8 batches x 16 cols,
// split-K x2 (halves reduced through LDS). h_{t-1} rows staged in LDS (pad 1028
// keeps the 4 distinct row reads per wave on distinct banks, 16B-aligned).
__global__ __launch_bounds__(256) void rnn_step(const float* __restrict__ Wh,
                                                const float* __restrict__ WhT,
                                                float* __restrict__ out, int t) {
    __shared__ float hs[8][1028];
    __shared__ float ps[256];
    const int tid = threadIdx.x;
    const int n0 = blockIdx.x * 16;
    const int b0 = blockIdx.y * 8;

    // stage h_prev = out[b0..b0+7][t-1][:]
    for (int i = tid; i < 8 * 256; i += 256) {
        int r = i >> 8;
        int c = (i & 255) << 2;
        *(float4*)&hs[r][c] =
            *(const float4*)(out + ((size_t)(b0 + r) * SS + (t - 1)) * HH + c);
    }
    __syncthreads();

    const int nl = tid & 15;
    const int bl = (tid >> 4) & 7;
    const int half = tid >> 7;          // split-K
    const int n = n0 + nl;

    float acc = 0.f;
    const float* hrow = &hs[bl][half * 512];
    if (WhT) {
        const float* wrow = WhT + (size_t)n * HH + half * 512;
#pragma unroll 4
        for (int k = 0; k < 512; k += 4) {
            float4 w4 = *(const float4*)(wrow + k);
            float4 h4 = *(const float4*)(hrow + k);
            acc += h4.x * w4.x + h4.y * w4.y + h4.z * w4.z + h4.w * w4.w;
        }
    } else {
        const float* wcol = Wh + (size_t)(half * 512) * HH + n;
#pragma unroll 4
        for (int k = 0; k < 512; k += 4) {
            float4 h4 = *(const float4*)(hrow + k);
            acc += h4.x * wcol[(size_t)(k + 0) * HH];
            acc += h4.y * wcol[(size_t)(k + 1) * HH];
            acc += h4.z * wcol[(size_t)(k + 2) * HH];
            acc += h4.w * wcol[(size_t)(k + 3) * HH];
        }
    }
    ps[tid] = acc;
    __syncthreads();

    if (tid < 128) {
        const size_t obase = ((size_t)(b0 + bl) * SS + t) * HH + n;
        out[obase] = tanhf(out[obase] + ps[tid] + ps[tid + 128]);
    }
}

extern "C" void kernel_launch(void* const* d_in, const int* in_sizes, int n_in,
                              void* d_out, int out_size, void* d_ws, size_t ws_size,
                              hipStream_t stream) {
    const float* x    = (const float*)d_in[0];
    const float* Wx   = (const float*)d_in[1];
    const float* Wh   = (const float*)d_in[2];
    const float* bias = (const float*)d_in[3];
    const float* h0   = (const float*)d_in[4];
    float* out = (float*)d_out;
    float* ws  = (float*)d_ws;

    // Phase 1: Xp = x@Wx + b into d_out. Grid 8 x 256 (N/128 x M/128).
    xw_gemm<<<dim3(8, 256), 256, 0, stream>>>(x, Wx, bias, out);

    // c = h0@Wh into ws[0..1023] (zeroed first; atomic accumulation).
    float* cvec = ws;
    hipMemsetAsync(cvec, 0, HH * sizeof(float), stream);
    h0wh<<<64, 256, 0, stream>>>(Wh, h0, cvec);

    // Transposed Wh for the step kernel if workspace permits (probe ws_size:
    // the transpose dispatch shows up in rocprof iff this path ran).
    float* WhT = nullptr;
    if (ws_size >= (size_t)HH * sizeof(float) + (size_t)HH * HH * sizeof(float)) {
        WhT = ws + HH;
        transpose_wh<<<dim3(32, 32), 256, 0, stream>>>(Wh, WhT);
    }

    // t = 0
    t0_kernel<<<BB * HH / 256, 256, 0, stream>>>(out, cvec);

    // t = 1..S-1 (sequential, one launch each — baseline)
    for (int t = 1; t < SS; ++t)
        rnn_step<<<dim3(64, 4), 256, 0, stream>>>(Wh, WhT, out, t);
}